// Round 5
// baseline (267.932 us; speedup 1.0000x reference)
//
#include <hip/hip_runtime.h>
#include <math.h>

#define Mv 8
#define Nv 8192
#define Kv 256
#define BPM 128          // blocks per m in p1 -> 1024 blocks total (4/CU)
#define NITER 6
#define EPSILON_C 0.01f
#define GAMMA_C 0.005f

// ws layout (float offsets)
#define WS_R     0        // 72   (M x 3 x 3 row-major)
#define WS_T     72       // 24   (M x 3)
#define WS_X     96       // 768  (K x 3)
#define WS_Q     864      // 256
#define WS_BETA  1120     // 1
#define WS_STATS 1124     // 128  (M x 16) per-m reduced stats
#define WS_L     1252     // 2048 (M x K)
#define WS_W     3300     // 6144 (M x 3 x K)  -- raw (no Q scaling)
#define WS_H     9444     // 2048 (M x K)
#define WS_ZERO_N (128+2048+6144+2048)   // zero from WS_STATS

// ---- wave-wide sum via DPP; wave-uniform result. All lanes must be active.
__device__ __forceinline__ float wave_red_sum(float x) {
  int v;
  float t;
  v = __builtin_bit_cast(int, x);
  t = __builtin_bit_cast(float, __builtin_amdgcn_update_dpp(0, v, 0x111, 0xf, 0xf, true));  // row_shr:1
  x += t; v = __builtin_bit_cast(int, x);
  t = __builtin_bit_cast(float, __builtin_amdgcn_update_dpp(0, v, 0x112, 0xf, 0xf, true));  // row_shr:2
  x += t; v = __builtin_bit_cast(int, x);
  t = __builtin_bit_cast(float, __builtin_amdgcn_update_dpp(0, v, 0x114, 0xf, 0xf, true));  // row_shr:4
  x += t; v = __builtin_bit_cast(int, x);
  t = __builtin_bit_cast(float, __builtin_amdgcn_update_dpp(0, v, 0x118, 0xf, 0xf, true));  // row_shr:8
  x += t; v = __builtin_bit_cast(int, x);
  t = __builtin_bit_cast(float, __builtin_amdgcn_update_dpp(0, v, 0x142, 0xa, 0xf, false)); // row_bcast:15
  x += t; v = __builtin_bit_cast(int, x);
  t = __builtin_bit_cast(float, __builtin_amdgcn_update_dpp(0, v, 0x143, 0xc, 0xf, false)); // row_bcast:31
  x += t;
  return __builtin_bit_cast(float, __builtin_amdgcn_readlane(__builtin_bit_cast(int, x), 63));
}

// ---------------------------------------------------------------- init
__global__ __launch_bounds__(256) void p0_init(const float* __restrict__ Vs,
                                               const float* __restrict__ X0,
                                               const float* __restrict__ Q0,
                                               float* __restrict__ ws) {
  __shared__ float sred[4];
  int tid = threadIdx.x;
  int b = blockIdx.x;
  int wave = tid >> 6, lane = tid & 63;
  if (b < 24) {
    int m = b / 3, d = b % 3;
    const float* src = Vs + (size_t)(m*3 + d) * Nv;
    float s = 0.f;
    for (int n = tid; n < Nv; n += 256) s += src[n];
    s = wave_red_sum(s);
    if (lane == 0) sred[wave] = s;
    __syncthreads();
    if (tid == 0) {
      float tot = sred[0]+sred[1]+sred[2]+sred[3];
      ws[WS_T + m*3 + d] = -tot / (float)Nv;
    }
    if (d == 0 && tid < 9) {
      ws[WS_R + m*9 + tid] = (tid==0||tid==4||tid==8) ? 1.f : 0.f;
    }
  } else {
    float s = (tid < Kv) ? Q0[tid] : 0.f;
    s = wave_red_sum(s);
    if (lane == 0) sred[wave] = s;
    __syncthreads();
    if (tid == 0) {
      float mq = (sred[0]+sred[1]+sred[2]+sred[3]) / (float)Kv;
      ws[WS_BETA] = GAMMA_C * mq * sqrtf(mq);
    }
    if (tid < Kv) ws[WS_Q + tid] = Q0[tid];
    for (int i = tid; i < Kv*3; i += 256) ws[WS_X + i] = X0[i];
    for (int i = tid; i < WS_ZERO_N; i += 256) ws[WS_STATS + i] = 0.f;
  }
}

// ------------------------------------------------- big fused pass (per iter)
// One wave per point-slice; lane l owns k in {l, l+64, l+128, l+192}.
// Accumulates L, Wraw, H in registers; block reduce; atomicAdd to ws.
// ALSO accumulates this block's partial of the 16 per-m stats.
__global__ __launch_bounds__(256) void p1_accum(const float* __restrict__ Vs,
                                                float* __restrict__ ws) {
  __shared__ float sb[4][5][Kv]; // 20 KB
  __shared__ float st4[4][16];
  int m    = blockIdx.x / BPM;
  int blk  = blockIdx.x % BPM;
  int wave = threadIdx.x >> 6;
  int lane = threadIdx.x & 63;
  int wid  = blk*4 + wave;   // 0..(BPM*4-1) within this m

  float R00 = ws[WS_R+m*9+0], R01 = ws[WS_R+m*9+1], R02 = ws[WS_R+m*9+2];
  float R10 = ws[WS_R+m*9+3], R11 = ws[WS_R+m*9+4], R12 = ws[WS_R+m*9+5];
  float R20 = ws[WS_R+m*9+6], R21 = ws[WS_R+m*9+7], R22 = ws[WS_R+m*9+8];
  float t0 = ws[WS_T+m*3+0], t1 = ws[WS_T+m*3+1], t2 = ws[WS_T+m*3+2];
  float beta = ws[WS_BETA];

  float kXx[4],kXy[4],kXz[4],kA[4],kB[4],kQ[4],kQ32[4];
  #pragma unroll
  for (int j=0;j<4;j++) {
    int k = lane + 64*j;
    float xx = ws[WS_X+k*3+0], xy = ws[WS_X+k*3+1], xz = ws[WS_X+k*3+2];
    float q  = ws[WS_Q+k];
    kXx[j]=xx; kXy[j]=xy; kXz[j]=xz;
    kA[j]  = -0.5f*q;
    kB[j]  = kA[j]*(xx*xx+xy*xy+xz*xz);
    kQ[j]  = q;
    kQ32[j]= q*sqrtf(q);
  }
  float aL[4]={0,0,0,0}, aWx[4]={0,0,0,0}, aWy[4]={0,0,0,0},
        aWz[4]={0,0,0,0}, aH[4]={0,0,0,0};
  const float* V0 = Vs + (size_t)(m*3+0)*Nv;
  const float* V1 = Vs + (size_t)(m*3+1)*Nv;
  const float* V2 = Vs + (size_t)(m*3+2)*Nv;

  for (int n = wid; n < Nv; n += BPM*4) {
    float vx = V0[n], vy = V1[n], vz = V2[n];
    float px = fmaf(R00,vx, fmaf(R01,vy, fmaf(R02,vz, t0)));
    float py = fmaf(R10,vx, fmaf(R11,vy, fmaf(R12,vz, t1)));
    float pz = fmaf(R20,vx, fmaf(R21,vy, fmaf(R22,vz, t2)));
    float tvn = fmaf(px,px, fmaf(py,py, pz*pz));
    float vn  = fmaf(vx,vx, fmaf(vy,vy, vz*vz));
    float ap[4]; float s = 0.f;
    #pragma unroll
    for (int j=0;j<4;j++) {
      float dot = fmaf(px,kXx[j], fmaf(py,kXy[j], pz*kXz[j]));
      float arg = fmaf(kQ[j], dot, fmaf(kA[j], tvn, kB[j]));
      float e = __expf(arg)*kQ32[j];
      ap[j] = e; s += e;
    }
    float S = wave_red_sum(s);          // wave-uniform
    float inv = 1.f/(S + beta);
    #pragma unroll
    for (int j=0;j<4;j++) {
      float a = ap[j]*inv;
      aL[j] += a;
      aWx[j] = fmaf(a,vx,aWx[j]);
      aWy[j] = fmaf(a,vy,aWy[j]);
      aWz[j] = fmaf(a,vz,aWz[j]);
      aH[j]  = fmaf(a,vn,aH[j]);
    }
  }
  #pragma unroll
  for (int j=0;j<4;j++) {
    int k = lane + 64*j;
    sb[wave][0][k]=aL[j];  sb[wave][1][k]=aWx[j]; sb[wave][2][k]=aWy[j];
    sb[wave][3][k]=aWz[j]; sb[wave][4][k]=aH[j];
  }
  __syncthreads();
  int k = threadIdx.x;
  float vL  = sb[0][0][k]+sb[1][0][k]+sb[2][0][k]+sb[3][0][k];
  float vWx = sb[0][1][k]+sb[1][1][k]+sb[2][1][k]+sb[3][1][k];
  float vWy = sb[0][2][k]+sb[1][2][k]+sb[2][2][k]+sb[3][2][k];
  float vWz = sb[0][3][k]+sb[1][3][k]+sb[2][3][k]+sb[3][3][k];
  float vH  = sb[0][4][k]+sb[1][4][k]+sb[2][4][k]+sb[3][4][k];
  atomicAdd(&ws[WS_L + m*Kv + k], vL);
  atomicAdd(&ws[WS_W + (m*3+0)*Kv + k], vWx);
  atomicAdd(&ws[WS_W + (m*3+1)*Kv + k], vWy);
  atomicAdd(&ws[WS_W + (m*3+2)*Kv + k], vWz);
  atomicAdd(&ws[WS_H + m*Kv + k], vH);

  // ---- block-partial 16 stats for this m
  float q  = ws[WS_Q + k];
  float x0 = ws[WS_X + k*3+0], x1 = ws[WS_X + k*3+1], x2 = ws[WS_X + k*3+2];
  float bk = vL*q;
  float sw0 = vWx*q, sw1 = vWy*q, sw2 = vWz*q;
  float pr[16];
  pr[0]=bk;  pr[1]=bk*x0; pr[2]=bk*x1; pr[3]=bk*x2;
  pr[4]=sw0; pr[5]=sw1;   pr[6]=sw2;
  pr[7]=sw0*x0;  pr[8]=sw1*x0;  pr[9]=sw2*x0;
  pr[10]=sw0*x1; pr[11]=sw1*x1; pr[12]=sw2*x1;
  pr[13]=sw0*x2; pr[14]=sw1*x2; pr[15]=sw2*x2;
  float red[16];
  #pragma unroll
  for (int v2=0; v2<16; v2++) red[v2] = wave_red_sum(pr[v2]);
  if (lane == 0) {
    #pragma unroll
    for (int v2=0; v2<16; v2++) st4[wave][v2] = red[v2];
  }
  __syncthreads();
  if (k < 16)
    atomicAdd(&ws[WS_STATS + m*16 + k],
              st4[0][k]+st4[1][k]+st4[2][k]+st4[3][k]);
}

// ---- fp32 Jacobi rotation, COMPILE-TIME pair, named scalars only (no
// runtime-indexed arrays -> no scratch). Native-rate rcp/rsq/sqrt: the fp64
// version's div/sqrt dependent chain (~350cyc/rot, ~140 VGPRs of live state,
// spilled at VGPR_Count=68) was the single-block p2's ~30us floor (R1-R4).
#define JROTF(app,aqq,apq,apr,aqr, vp0,vp1,vp2, vq0,vq1,vq2) do {           \
    float tau_ = (aqq - app) * __builtin_amdgcn_rcpf(2.0f*apq);             \
    float tt_ = __builtin_amdgcn_rcpf(fabsf(tau_) +                         \
                   __builtin_amdgcn_sqrtf(fmaf(tau_,tau_,1.0f)));           \
    tt_ = (tau_ < 0.0f) ? -tt_ : tt_;                                       \
    tt_ = (apq == 0.0f) ? 0.0f : tt_;                                       \
    float c_ = __builtin_amdgcn_rsqf(fmaf(tt_,tt_,1.0f)), s_ = tt_*c_;      \
    float papq_ = apq;                                                      \
    app = fmaf(-tt_,papq_,app); aqq = fmaf(tt_,papq_,aqq); apq = 0.0f;      \
    float tp_ = apr, tq_ = aqr;                                             \
    apr = c_*tp_ - s_*tq_; aqr = s_*tp_ + c_*tq_;                           \
    tp_=vp0; tq_=vq0; vp0=c_*tp_-s_*tq_; vq0=s_*tp_+c_*tq_;                 \
    tp_=vp1; tq_=vq1; vp1=c_*tp_-s_*tq_; vq1=s_*tp_+c_*tq_;                 \
    tp_=vp2; tq_=vq2; vp2=c_*tp_-s_*tq_; vq2=s_*tp_+c_*tq_;                 \
  } while(0)

#define CSWAP3F(la,lb, a0,a1,a2, b0,b1,b2) do {                             \
    if (la < lb) { float t_;                                                \
      t_=la; la=lb; lb=t_; t_=a0; a0=b0; b0=t_;                             \
      t_=a1; a1=b1; b1=t_; t_=a2; a2=b2; b2=t_; }                           \
  } while(0)

// --------------------------------------- per-iteration small update (1 block)
__global__ __launch_bounds__(256) void p2_update(float* __restrict__ ws, int iter) {
  __shared__ float sR[Mv][9];
  __shared__ float sT[Mv][3];
  __shared__ float sTn[Mv];
  int tid = threadIdx.x;
  const int k = tid;

  // ---- independent coalesced preloads (consumed after the barrier; their
  // latency hides under the 8-lane SVD)
  float lk[Mv], w0v[Mv], w1v[Mv], w2v[Mv], hk[Mv];
  #pragma unroll
  for (int m=0;m<Mv;m++) {
    lk[m]  = ws[WS_L + m*Kv + k];
    w0v[m] = ws[WS_W + (m*3+0)*Kv + k];
    w1v[m] = ws[WS_W + (m*3+1)*Kv + k];
    w2v[m] = ws[WS_W + (m*3+2)*Kv + k];
    hk[m]  = ws[WS_H + m*Kv + k];
  }
  float xp0 = ws[WS_X + k*3+0], xp1 = ws[WS_X + k*3+1], xp2 = ws[WS_X + k*3+2];

  if (tid < Mv) {
    int m = tid;
    float* st = ws + WS_STATS + m*16;
    float s0=st[0], s1=st[1], s2v=st[2], s3=st[3], s4=st[4], s5=st[5], s6=st[6],
          s7=st[7], s8=st[8], s9=st[9], s10=st[10], s11=st[11], s12=st[12],
          s13=st[13], s14=st[14], s15=st[15];
    // zero stats for next p1's atomics
    st[0]=0;st[1]=0;st[2]=0;st[3]=0;st[4]=0;st[5]=0;st[6]=0;st[7]=0;
    st[8]=0;st[9]=0;st[10]=0;st[11]=0;st[12]=0;st[13]=0;st[14]=0;st[15]=0;

    float z = s0;
    float mX0 = s1, mX1 = s2v, mX2 = s3;
    float mW0 = s4, mW1 = s5, mW2 = s6;
    float iz = 1.0f/z;
    float P00 = s7  - mX0*mW0*iz;
    float P01 = s8  - mX0*mW1*iz;
    float P02 = s9  - mX0*mW2*iz;
    float P10 = s10 - mX1*mW0*iz;
    float P11 = s11 - mX1*mW1*iz;
    float P12 = s12 - mX1*mW2*iz;
    float P20 = s13 - mX2*mW0*iz;
    float P21 = s14 - mX2*mW1*iz;
    float P22 = s15 - mX2*mW2*iz;

    // S = P^T P (symmetric)
    float a00 = P00*P00 + P10*P10 + P20*P20;
    float a01 = P00*P01 + P10*P11 + P20*P21;
    float a02 = P00*P02 + P10*P12 + P20*P22;
    float a11 = P01*P01 + P11*P11 + P21*P21;
    float a12 = P01*P02 + P11*P12 + P21*P22;
    float a22 = P02*P02 + P12*P12 + P22*P22;
    float v00=1, v01=0, v02=0, v10=0, v11=1, v12=0, v20=0, v21=0, v22=1;
    #pragma unroll 1
    for (int sweep = 0; sweep < 8; sweep++) {
      JROTF(a00,a11,a01, a02,a12, v00,v10,v20, v01,v11,v21);  // pair (0,1)
      JROTF(a00,a22,a02, a01,a12, v00,v10,v20, v02,v12,v22);  // pair (0,2)
      JROTF(a11,a22,a12, a01,a02, v01,v11,v21, v02,v12,v22);  // pair (1,2)
    }
    float l0 = a00, l1 = a11, l2 = a22;
    CSWAP3F(l0,l1, v00,v10,v20, v01,v11,v21);
    CSWAP3F(l1,l2, v01,v11,v21, v02,v12,v22);
    CSWAP3F(l0,l1, v00,v10,v20, v01,v11,v21);
    float detP = P00*(P11*P22-P12*P21) - P01*(P10*P22-P12*P20)
               + P02*(P10*P21-P11*P20);
    float s2d = (detP < 0.0f) ? -1.0f : 1.0f;
    float tiny = 1e-18f*l0 + 1e-30f;
    float w0i = __builtin_amdgcn_rsqf(fmaxf(l0,tiny));
    float w1i = __builtin_amdgcn_rsqf(fmaxf(l1,tiny));
    float w2i = s2d*__builtin_amdgcn_rsqf(fmaxf(l2,tiny));
    float M00 = w0i*v00*v00 + w1i*v01*v01 + w2i*v02*v02;
    float M01 = w0i*v00*v10 + w1i*v01*v11 + w2i*v02*v12;
    float M02 = w0i*v00*v20 + w1i*v01*v21 + w2i*v02*v22;
    float M11 = w0i*v10*v10 + w1i*v11*v11 + w2i*v12*v12;
    float M12 = w0i*v10*v20 + w1i*v11*v21 + w2i*v12*v22;
    float M22 = w0i*v20*v20 + w1i*v21*v21 + w2i*v22*v22;
    float R00 = P00*M00 + P01*M01 + P02*M02;
    float R01 = P00*M01 + P01*M11 + P02*M12;
    float R02 = P00*M02 + P01*M12 + P02*M22;
    float R10 = P10*M00 + P11*M01 + P12*M02;
    float R11 = P10*M01 + P11*M11 + P12*M12;
    float R12 = P10*M02 + P11*M12 + P12*M22;
    float R20 = P20*M00 + P21*M01 + P22*M02;
    float R21 = P20*M01 + P21*M11 + P22*M12;
    float R22 = P20*M02 + P21*M12 + P22*M22;
    float tm0 = (mX0 - (R00*mW0 + R01*mW1 + R02*mW2))*iz;
    float tm1 = (mX1 - (R10*mW0 + R11*mW1 + R12*mW2))*iz;
    float tm2 = (mX2 - (R20*mW0 + R21*mW1 + R22*mW2))*iz;
    sR[m][0]=R00; ws[WS_R+m*9+0]=R00;
    sR[m][1]=R01; ws[WS_R+m*9+1]=R01;
    sR[m][2]=R02; ws[WS_R+m*9+2]=R02;
    sR[m][3]=R10; ws[WS_R+m*9+3]=R10;
    sR[m][4]=R11; ws[WS_R+m*9+4]=R11;
    sR[m][5]=R12; ws[WS_R+m*9+5]=R12;
    sR[m][6]=R20; ws[WS_R+m*9+6]=R20;
    sR[m][7]=R21; ws[WS_R+m*9+7]=R21;
    sR[m][8]=R22; ws[WS_R+m*9+8]=R22;
    sT[m][0]=tm0; ws[WS_T+m*3+0]=tm0;
    sT[m][1]=tm1; ws[WS_T+m*3+1]=tm1;
    sT[m][2]=tm2; ws[WS_T+m*3+2]=tm2;
    sTn[m] = tm0*tm0 + tm1*tm1 + tm2*tm2;
  }
  __syncthreads();

  // ---- per-k X/Q update from preloaded registers
  float den = 0.f, Xn0=0.f, Xn1=0.f, Xn2=0.f, S2=0.f;
  #pragma unroll
  for (int m=0;m<Mv;m++) {
    float r0 = sR[m][0]*w0v[m] + sR[m][1]*w1v[m] + sR[m][2]*w2v[m];
    float r1 = sR[m][3]*w0v[m] + sR[m][4]*w1v[m] + sR[m][5]*w2v[m];
    float r2 = sR[m][6]*w0v[m] + sR[m][7]*w1v[m] + sR[m][8]*w2v[m];
    float t0 = sT[m][0], t1 = sT[m][1], t2 = sT[m][2];
    den += lk[m];
    Xn0 += r0 + t0*lk[m]; Xn1 += r1 + t1*lk[m]; Xn2 += r2 + t2*lk[m];
    S2  += hk[m] + 2.f*(t0*r0+t1*r1+t2*r2) + sTn[m]*lk[m];
  }
  float x0, x1, x2;
  if (iter > 1) { float inv = 1.f/den; x0=Xn0*inv; x1=Xn1*inv; x2=Xn2*inv; }
  else          { x0=xp0; x1=xp1; x2=xp2; }
  float wn = S2 + (x0*x0+x1*x1+x2*x2)*den - 2.f*(x0*Xn0+x1*Xn1+x2*Xn2);
  float qn = 3.f*den / (wn + 3.f*den*EPSILON_C);
  ws[WS_X + k*3+0]=x0; ws[WS_X + k*3+1]=x1; ws[WS_X + k*3+2]=x2;
  ws[WS_Q + k] = qn;
  // zero L/W/H in place for the next p1
  #pragma unroll
  for (int m=0;m<Mv;m++) {
    ws[WS_L + m*Kv + k] = 0.f;
    ws[WS_W + (m*3+0)*Kv + k] = 0.f;
    ws[WS_W + (m*3+1)*Kv + k] = 0.f;
    ws[WS_W + (m*3+2)*Kv + k] = 0.f;
    ws[WS_H + m*Kv + k] = 0.f;
  }
}

// ---------------------------------------------------------------- final out
__global__ __launch_bounds__(256) void p3_final(const float* __restrict__ Vs,
                                                const float* __restrict__ ws,
                                                float* __restrict__ out) {
  int idx = blockIdx.x*256 + threadIdx.x;
  if (idx < Mv*3*Nv) {
    int m = idx / (3*Nv);
    int r = idx % (3*Nv);
    int d = r / Nv;
    int n = r % Nv;
    float vx = Vs[(size_t)(m*3+0)*Nv + n];
    float vy = Vs[(size_t)(m*3+1)*Nv + n];
    float vz = Vs[(size_t)(m*3+2)*Nv + n];
    out[idx] = fmaf(ws[WS_R+m*9+d*3+0],vx,
               fmaf(ws[WS_R+m*9+d*3+1],vy,
               fmaf(ws[WS_R+m*9+d*3+2],vz, ws[WS_T+m*3+d])));
  } else if (idx < Mv*3*Nv + 72 + 24 + Kv*3) {
    int j = idx - Mv*3*Nv;
    float v;
    if (j < 72)      v = ws[WS_R + j];
    else if (j < 96) v = ws[WS_T + (j-72)];
    else             v = ws[WS_X + (j-96)];
    out[idx] = v;
  }
}

extern "C" void kernel_launch(void* const* d_in, const int* in_sizes, int n_in,
                              void* d_out, int out_size, void* d_ws, size_t ws_size,
                              hipStream_t stream) {
  const float* Vs = (const float*)d_in[0];
  const float* X0 = (const float*)d_in[1];
  const float* Q0 = (const float*)d_in[2];
  float* out = (float*)d_out;
  float* ws  = (float*)d_ws;

  p0_init<<<25, 256, 0, stream>>>(Vs, X0, Q0, ws);
  for (int i = 0; i < NITER; i++) {
    p1_accum<<<Mv*BPM, 256, 0, stream>>>(Vs, ws);
    p2_update<<<1, 256, 0, stream>>>(ws, i);
  }
  int total = Mv*3*Nv + 72 + 24 + Kv*3;
  p3_final<<<(total + 255)/256, 256, 0, stream>>>(Vs, ws, out);
}